// Round 4
// baseline (60.008 us; speedup 1.0000x reference)
//
#include <hip/hip_runtime.h>
#include <hip/hip_bf16.h>
#include <math.h>

#define NROW 256
#define DIM  65536
#define BK   64          // k-floats per LDS step

typedef __attribute__((ext_vector_type(8))) short short8;
typedef __attribute__((ext_vector_type(4))) float f32x4;
typedef unsigned int       u32t;
typedef unsigned long long u64t;

__device__ __forceinline__ float bf2f(ushort h) {
    u32t u = ((u32t)h) << 16;
    return __builtin_bit_cast(float, u);
}
// packed fp32x2 -> bf16x2 (compiler emits v_cvt_pk_bf16_f32, RNE)
__device__ __forceinline__ u32t pk2(float lo, float hi) {
    __hip_bfloat162 h = __float22bfloat162_rn(make_float2(lo, hi));
    u32t r;
    __builtin_memcpy(&r, &h, 4);
    return r;
}

// native-layout position of G[i][j] (matches gemm epilogue store order)
__device__ __forceinline__ int gpos(int i, int j) {
    const int wid  = ((i >> 7) << 2) | (j >> 6);
    const int lane = (((i >> 2) & 3) << 4) | (j & 15);
    const int m = (i >> 4) & 7, n = (j >> 4) & 3, jr = i & 3;
    return ((wid << 6) | lane) * 128 + (((m << 2) | n) << 2) + jr;
}

// ---------------------------------------------------------------------------
// Split-K MFMA GEMM: block s computes the FULL 256x256 = E*E^T over its
// K-chunk. E (fp32) read from HBM exactly once, converted to bf16 into a
// XOR-swizzled LDS tile (16B-granule swizzle g^=row&7 -> conflict-balanced
// b128 frag reads AND b64 staging writes, 64 KiB total). Double-buffered,
// 1-step lookahead. Partials written bf16 in thread-native layout.
// ---------------------------------------------------------------------------
__global__ __launch_bounds__(512) void gemm_mfma(const float* __restrict__ E,
                                                 ushort* __restrict__ part,
                                                 int stepsPer, int extra) {
    const int s      = blockIdx.x;
    const int step0  = s * stepsPer + (s < extra ? s : extra);
    const int nsteps = stepsPer + (s < extra ? 1 : 0);

    const int tid  = threadIdx.x;
    const int lane = tid & 63;
    const int wid  = tid >> 6;
    const int wr   = wid >> 2;           // 0..1 -> 128-row band
    const int wc   = wid & 3;            // 0..3 -> 64-col band
    const int r15  = lane & 15;
    const int kgi  = lane >> 4;          // 0..3 -> 16B granule within 32-k slice

    // staging coords: granule G = i*512+tid -> row = i*32 + (tid>>4), 16B col (tid&15)
    const int rhi = tid >> 4;            // 0..31
    const int cg  = (tid & 15) >> 1;     // logical 16B granule 0..7
    const int ch  = tid & 1;             // 8B half within granule

    __shared__ ushort Es[2][NROW][BK];   // 64 KiB, swizzled at 16B granules

    f32x4 acc[8][4];
    #pragma unroll
    for (int m = 0; m < 8; ++m)
        #pragma unroll
        for (int n = 0; n < 4; ++n) acc[m][n] = (f32x4){0.f, 0.f, 0.f, 0.f};

    const float* gbase = E + (size_t)rhi * DIM + (tid & 15) * 4;

    float4 v[8], vn[8];
    {   // prologue: load + stage step0 into buf 0
        const size_t kb = (size_t)step0 * BK;
        #pragma unroll
        for (int i = 0; i < 8; ++i)
            v[i] = *(const float4*)(gbase + (size_t)i * 32 * DIM + kb);
        #pragma unroll
        for (int i = 0; i < 8; ++i) {
            const int row = i * 32 + rhi;
            uint2 w; w.x = pk2(v[i].x, v[i].y); w.y = pk2(v[i].z, v[i].w);
            *(uint2*)&Es[0][row][((cg ^ (row & 7)) << 3) + ch * 4] = w;
        }
    }

    for (int t = 0; t < nsteps; ++t) {
        const int b = t & 1;
        if (t + 1 < nsteps) {            // issue next chunk's loads early
            const size_t kb = (size_t)(step0 + t + 1) * BK;
            #pragma unroll
            for (int i = 0; i < 8; ++i)
                vn[i] = *(const float4*)(gbase + (size_t)i * 32 * DIM + kb);
        }
        __syncthreads();                 // buf b staged; prev reads of b^1 done

        #pragma unroll
        for (int kk = 0; kk < 2; ++kk) {
            short8 af[8], bfr[4];
            #pragma unroll
            for (int m = 0; m < 8; ++m) {
                const int row = wr * 128 + m * 16 + r15;
                af[m] = *(const short8*)&Es[b][row][(((kk << 2) | kgi) ^ (row & 7)) << 3];
            }
            #pragma unroll
            for (int n = 0; n < 4; ++n) {
                const int row = wc * 64 + n * 16 + r15;
                bfr[n] = *(const short8*)&Es[b][row][(((kk << 2) | kgi) ^ (row & 7)) << 3];
            }
            #pragma unroll
            for (int m = 0; m < 8; ++m)
                #pragma unroll
                for (int n = 0; n < 4; ++n)
                    acc[m][n] = __builtin_amdgcn_mfma_f32_16x16x32_bf16(
                        af[m], bfr[n], acc[m][n], 0, 0, 0);
        }

        if (t + 1 < nsteps) {            // stage next chunk into other buffer
            #pragma unroll
            for (int i = 0; i < 8; ++i) {
                const int row = i * 32 + rhi;
                uint2 w; w.x = pk2(vn[i].x, vn[i].y); w.y = pk2(vn[i].z, vn[i].w);
                *(uint2*)&Es[b ^ 1][row][((cg ^ (row & 7)) << 3) + ch * 4] = w;
            }
        }
    }

    // epilogue: 128 accs -> bf16, contiguous per-thread (coalesced 16B stores)
    ushort* pp = part + (size_t)s * (NROW * NROW) + (size_t)tid * 128;
    #pragma unroll
    for (int m = 0; m < 8; ++m)
        #pragma unroll
        for (int n = 0; n < 4; n += 2) {
            uint4 q;
            q.x = pk2(acc[m][n][0],     acc[m][n][1]);
            q.y = pk2(acc[m][n][2],     acc[m][n][3]);
            q.z = pk2(acc[m][n + 1][0], acc[m][n + 1][1]);
            q.w = pk2(acc[m][n + 1][2], acc[m][n + 1][3]);
            *(uint4*)(pp + ((m << 2) | n) * 4) = q;
        }
}

// Fixed-order sum of P bf16 partials -> Gn (fp32, native layout). Also zeroes
// the fixed-point accumulator for the fused row_loss kernel (stream-ordered).
__global__ __launch_bounds__(256) void reduce_k(const ushort* __restrict__ part,
                                                float* __restrict__ Gn,
                                                u64t* __restrict__ acc,
                                                u32t* __restrict__ cnt, int P) {
    if (blockIdx.x == 0 && threadIdx.x == 0) { *acc = 0ull; *cnt = 0u; }

    const int b = blockIdx.x, t = threadIdx.x;
    const int l = t & 63, sg = t >> 6;
    const int n0 = b * 256 + l * 4;

    float a0 = 0.f, a1 = 0.f, a2 = 0.f, a3 = 0.f;
    for (int s = sg; s < P; s += 4) {
        const ushort4 u = *(const ushort4*)&part[(size_t)s * (NROW * NROW) + n0];
        a0 += bf2f(u.x); a1 += bf2f(u.y); a2 += bf2f(u.z); a3 += bf2f(u.w);
    }
    __shared__ float sh[4][256];
    sh[sg][l * 4 + 0] = a0; sh[sg][l * 4 + 1] = a1;
    sh[sg][l * 4 + 2] = a2; sh[sg][l * 4 + 3] = a3;
    __syncthreads();
    Gn[b * 256 + t] = (sh[0][t] + sh[1][t]) + (sh[2][t] + sh[3][t]);
}

// ---------------------------------------------------------------------------
// Fused per-row softmax loss + deterministic final sum. Row losses quantized
// to 2^-20 fixed point, integer-atomicAdd'ed (order-independent => bitwise
// deterministic); the last block (counter) converts and writes out[0].
// PSD term is provably 0 (AM-GM; clip at 0), omitted.
// ---------------------------------------------------------------------------
__global__ __launch_bounds__(256) void row_loss_k(const float* __restrict__ Gn,
                                                  const int* __restrict__ labels,
                                                  u64t* __restrict__ acc,
                                                  u32t* __restrict__ cnt,
                                                  float* __restrict__ out) {
    const int i = blockIdx.x;
    const int j = threadIdx.x;

    const float Gii = Gn[gpos(i, i)];
    const float Gjj = Gn[gpos(j, j)];
    const float Gij = Gn[gpos(i, j)];
    const float d2 = fmaxf(Gii + Gjj - 2.0f * Gij, 0.0f);
    const bool diag = (j == i);
    const float sc = diag ? -3.0e38f : -sqrtf(d2);

    __shared__ float red0[4], red1[4];

    float m = sc;
    #pragma unroll
    for (int off = 32; off; off >>= 1) m = fmaxf(m, __shfl_xor(m, off, 64));
    const int w = j >> 6;
    if ((j & 63) == 0) red0[w] = m;
    __syncthreads();
    m = fmaxf(fmaxf(red0[0], red0[1]), fmaxf(red0[2], red0[3]));

    const float p = diag ? 0.0f : expf(sc - m);
    const float nm = (labels[j] == labels[i]) ? p : 0.0f;

    float zs = p, ns = nm;
    #pragma unroll
    for (int off = 32; off; off >>= 1) {
        zs += __shfl_xor(zs, off, 64);
        ns += __shfl_xor(ns, off, 64);
    }
    __syncthreads();
    if ((j & 63) == 0) { red0[w] = zs; red1[w] = ns; }
    __syncthreads();
    if (j == 0) {
        const float Z = red0[0] + red0[1] + red0[2] + red0[3];
        const float N = red1[0] + red1[1] + red1[2] + red1[3];
        const float rl = logf(Z) - logf(N);          // >= 0 (N subset of Z)
        const long long q = llrintf(rl * 1048576.0f);
        atomicAdd(acc, (u64t)q);
        __threadfence();
        const u32t c = atomicAdd(cnt, 1u);
        if (c == NROW - 1) {                          // last block: all adds visible
            __threadfence();
            const u64t tot = atomicAdd(acc, 0ull);
            out[0] = (float)((double)(long long)tot * (1.0 / 1048576.0) * 0.005);
        }
    }
}

extern "C" void kernel_launch(void* const* d_in, const int* in_sizes, int n_in,
                              void* d_out, int out_size, void* d_ws, size_t ws_size,
                              hipStream_t stream) {
    const float* E      = (const float*)d_in[0];
    const int*   labels = (const int*)d_in[1];
    float*       out    = (float*)d_out;

    // pick largest split-K partial count that fits ws
    const int cands[6] = {256, 128, 64, 32, 16, 8};
    int P = 8;
    for (int ci = 0; ci < 6; ++ci) {
        const size_t need = (size_t)cands[ci] * NROW * NROW * sizeof(ushort)
                          + (size_t)NROW * NROW * sizeof(float) + 64;
        if (need <= ws_size) { P = cands[ci]; break; }
    }
    const int stepsTotal = DIM / BK;            // 1024
    const int stepsPer   = stepsTotal / P;
    const int extra      = stepsTotal % P;

    ushort* part = (ushort*)d_ws;
    float*  Gn   = (float*)((char*)d_ws + (size_t)P * NROW * NROW * sizeof(ushort));
    u64t*   acc  = (u64t*)(Gn + NROW * NROW);
    u32t*   cnt  = (u32t*)(acc + 1);

    gemm_mfma <<<P, 512, 0, stream>>>(E, part, stepsPer, extra);
    reduce_k  <<<NROW, 256, 0, stream>>>(part, Gn, acc, cnt, P);
    row_loss_k<<<NROW, 256, 0, stream>>>(Gn, labels, acc, cnt, out);
}